// Round 1
// baseline (374.378 us; speedup 1.0000x reference)
//
#include <hip/hip_runtime.h>
#include <cstdint>
#include <cstddef>

// ---- constants from the reference config (exact fp32 images of the Python doubles) ----
#define C_DECAY 0.99f   // (1.0 - alpha), alpha = 1.0/100.0
#define C_ALPHA 0.01f   // alpha
#define C_THR   0.58f   // IGNITE_THR
#define C_WTA   0.85f   // WTA_INH

#define P1_TILE 128
#define P1_NPB  64

// ---------------- Phase 1: exact EMA chains, boundary states every L steps ----------------
// grid: N/64 blocks; block: 192 threads (wave0 = compute, waves 1-2 = loaders)
__global__ __launch_bounds__(192)
void gw_phase1(const float* __restrict__ spikes, const float* __restrict__ nmda0,
               float* __restrict__ bnd, float* __restrict__ nmda_final_out,
               int T, int N, int Ls) {
  __shared__ float4 sb[2][P1_TILE * P1_NPB / 4];   // 2 x 32 KiB
  const int w    = threadIdx.x >> 6;
  const int lane = threadIdx.x & 63;
  const int n0   = blockIdx.x * P1_NPB;
  const int ntiles = T / P1_TILE;
  const int N4 = N >> 2;
  const float4* sp4 = (const float4*)spikes;
  const int Lm1 = (1 << Ls) - 1;

  float nmda = 0.0f;
  if (w == 0) nmda = nmda0[n0 + lane];

  const int lid = (w - 1) * 64 + lane;   // [0,128) for loader waves

  // prologue: stage tile 0
  if (w > 0) {
    float4 r[16];
#pragma unroll
    for (int p = 0; p < 16; ++p) {
      int e = p * 128 + lid;
      int row = e >> 4, c4 = e & 15;
      r[p] = sp4[(size_t)row * N4 + (n0 >> 2) + c4];
    }
#pragma unroll
    for (int p = 0; p < 16; ++p) sb[0][p * 128 + lid] = r[p];
  }
  __syncthreads();

  for (int tile = 0; tile < ntiles; ++tile) {
    const int cur = tile & 1;
    if (w == 0) {
      const float* buf = (const float*)sb[cur];
      const int t0 = tile * P1_TILE;
#pragma unroll 16
      for (int k = 0; k < P1_TILE; ++k) {
        const int t = t0 + k;
        if ((t & Lm1) == 0) bnd[(size_t)(t >> Ls) * N + n0 + lane] = nmda;
        const float s  = buf[k * 64 + lane];
        const float t1 = __fmul_rn(C_DECAY, nmda);
        const float t2 = __fmul_rn(C_ALPHA, s);
        nmda = __fadd_rn(t1, t2);        // exact replica of the reference op order
      }
    } else if (tile + 1 < ntiles) {
      const int t0 = (tile + 1) * P1_TILE;
      float4 r[16];
#pragma unroll
      for (int p = 0; p < 16; ++p) {
        int e = p * 128 + lid;
        int row = e >> 4, c4 = e & 15;
        r[p] = sp4[(size_t)(t0 + row) * N4 + (n0 >> 2) + c4];
      }
#pragma unroll
      for (int p = 0; p < 16; ++p) sb[cur ^ 1][p * 128 + lid] = r[p];
    }
    __syncthreads();
  }
  if (w == 0) nmda_final_out[n0 + lane] = nmda;
}

// ---------------- Phase 2: recompute rows from exact boundary, stable top-2, write outputs ----------------
// grid: C = T/L blocks; block: N/4 = 1024 threads (16 waves)
__global__ __launch_bounds__(1024)
void gw_phase2(const float* __restrict__ spikes, const float* __restrict__ bnd,
               float* __restrict__ mask, float* __restrict__ cov,
               int T, int N, int L, float covval) {
  const int tid  = threadIdx.x;            // [0, N/4)
  const int lane = tid & 63;
  const int wv   = tid >> 6;               // wave id [0,16)
  const int c    = blockIdx.x;
  const int N4   = N >> 2;
  const float4* sp4 = (const float4*)spikes;
  float4* mk4 = (float4*)mask;

  __shared__ float ts1[16]; __shared__ int ti1[16];
  __shared__ float ts2[16]; __shared__ int ti2[16];
  __shared__ float tmx[16];
  __shared__ int b_i1[2], b_i2[2], b_ig[2];

  float4 nm = ((const float4*)bnd)[(size_t)c * N4 + tid];   // exact state before step c*L
  const int base = tid * 4;

  for (int r = 0; r < L; ++r) {
    const int t = c * L + r;
    const float4 s = sp4[(size_t)t * N4 + tid];

    // exact EMA update, bitwise identical to reference
    nm.x = __fadd_rn(__fmul_rn(C_DECAY, nm.x), __fmul_rn(C_ALPHA, s.x));
    nm.y = __fadd_rn(__fmul_rn(C_DECAY, nm.y), __fmul_rn(C_ALPHA, s.y));
    nm.z = __fadd_rn(__fmul_rn(C_DECAY, nm.z), __fmul_rn(C_ALPHA, s.z));
    nm.w = __fadd_rn(__fmul_rn(C_DECAY, nm.w), __fmul_rn(C_ALPHA, s.w));

    // scores (the reference top-k compares 0.85*nmda)
    const float c0 = __fmul_rn(nm.x, C_WTA);
    const float c1 = __fmul_rn(nm.y, C_WTA);
    const float c2 = __fmul_rn(nm.z, C_WTA);
    const float c3 = __fmul_rn(nm.w, C_WTA);

    // local max of UNSCALED values (for ignition test)
    float mx = fmaxf(fmaxf(nm.x, nm.y), fmaxf(nm.z, nm.w));

    // local stable top-2 (ascending index, strict > keeps lower index on ties)
    float a1 = c0; int i1 = base;
    float a2 = -__builtin_inff(); int i2 = 0x7fffffff;
    if (c1 > a1) { a2 = a1; i2 = i1; a1 = c1; i1 = base + 1; }
    else if (c1 > a2) { a2 = c1; i2 = base + 1; }
    if (c2 > a1) { a2 = a1; i2 = i1; a1 = c2; i1 = base + 2; }
    else if (c2 > a2) { a2 = c2; i2 = base + 2; }
    if (c3 > a1) { a2 = a1; i2 = i1; a1 = c3; i1 = base + 3; }
    else if (c3 > a2) { a2 = c3; i2 = base + 3; }

    // wave butterfly: merge top-2 tuples lexicographically (score desc, index asc)
#pragma unroll
    for (int m = 1; m < 64; m <<= 1) {
      const float ob1 = __shfl_xor(a1, m, 64); const int oi1 = __shfl_xor(i1, m, 64);
      const float ob2 = __shfl_xor(a2, m, 64); const int oi2 = __shfl_xor(i2, m, 64);
      const float omx = __shfl_xor(mx, m, 64);
      mx = fmaxf(mx, omx);
      const bool afirst = (a1 > ob1) || (a1 == ob1 && i1 < oi1);
      const float w1 = afirst ? a1 : ob1; const int wi1 = afirst ? i1 : oi1;
      const float l1 = afirst ? ob1 : a1; const int li1 = afirst ? oi1 : i1;
      const float cc = afirst ? a2 : ob2; const int ci = afirst ? i2 : oi2;
      const bool sfirst = (cc > l1) || (cc == l1 && ci < li1);
      a1 = w1; i1 = wi1;
      a2 = sfirst ? cc : l1; i2 = sfirst ? ci : li1;
    }
    if (lane == 0) { ts1[wv] = a1; ti1[wv] = i1; ts2[wv] = a2; ti2[wv] = i2; tmx[wv] = mx; }
    __syncthreads();

    if (wv == 0) {
      const int q = lane & 15;   // all 64 lanes load (dup per 16) to keep butterfly uniform
      float g1 = ts1[q]; int j1 = ti1[q];
      float g2 = ts2[q]; int j2 = ti2[q];
      float gm = tmx[q];
#pragma unroll
      for (int m = 1; m < 16; m <<= 1) {
        const float ob1 = __shfl_xor(g1, m, 64); const int oi1 = __shfl_xor(j1, m, 64);
        const float ob2 = __shfl_xor(g2, m, 64); const int oi2 = __shfl_xor(j2, m, 64);
        const float omx = __shfl_xor(gm, m, 64);
        gm = fmaxf(gm, omx);
        const bool afirst = (g1 > ob1) || (g1 == ob1 && j1 < oi1);
        const float w1 = afirst ? g1 : ob1; const int wi1 = afirst ? j1 : oi1;
        const float l1 = afirst ? ob1 : g1; const int li1 = afirst ? oi1 : j1;
        const float cc = afirst ? g2 : ob2; const int ci = afirst ? j2 : oi2;
        const bool sfirst = (cc > l1) || (cc == l1 && ci < li1);
        g1 = w1; j1 = wi1;
        g2 = sfirst ? cc : l1; j2 = sfirst ? ci : li1;
      }
      if (lane == 0) {
        const int ig = (gm >= C_THR) ? 1 : 0;
        b_i1[r & 1] = j1; b_i2[r & 1] = j2; b_ig[r & 1] = ig;
        cov[t] = ig ? covval : 0.0f;
      }
    }
    __syncthreads();

    const int ig = b_ig[r & 1];
    const int j1 = b_i1[r & 1];
    const int j2 = b_i2[r & 1];
    float4 v;
    v.x = (ig && (j1 == base     || j2 == base))     ? 1.0f : 0.0f;
    v.y = (ig && (j1 == base + 1 || j2 == base + 1)) ? 1.0f : 0.0f;
    v.z = (ig && (j1 == base + 2 || j2 == base + 2)) ? 1.0f : 0.0f;
    v.w = (ig && (j1 == base + 3 || j2 == base + 3)) ? 1.0f : 0.0f;
    mk4[(size_t)t * N4 + tid] = v;
  }
}

extern "C" void kernel_launch(void* const* d_in, const int* in_sizes, int n_in,
                              void* d_out, int out_size, void* d_ws, size_t ws_size,
                              hipStream_t stream) {
  const float* spikes = (const float*)d_in[0];
  const float* nmda0  = (const float*)d_in[1];
  const int N = in_sizes[1];
  const int T = in_sizes[0] / N;

  float* out  = (float*)d_out;
  float* mask = out;                               // [T, N]
  float* cov  = out + (size_t)T * N;               // [T]
  float* nmf  = cov + T;                           // [N]

  // boundary-state chunk length L = 1<<Ls; shrink boundary count if ws is small
  int Ls = 4;
  while (((size_t)(T >> Ls)) * (size_t)N * sizeof(float) > ws_size && Ls < 13) ++Ls;
  const int L = 1 << Ls;
  const int C = T / L;
  float* bnd = (float*)d_ws;                       // [C, N]

  gw_phase1<<<N / P1_NPB, 192, 0, stream>>>(spikes, nmda0, bnd, nmf, T, N, Ls);
  gw_phase2<<<C, N / 4, 0, stream>>>(spikes, bnd, mask, cov, T, N, L, 2.0f / (float)N);
}

// Round 2
// 162.704 us; speedup vs baseline: 2.3010x; 2.3010x over previous
//
#include <hip/hip_runtime.h>
#include <cstdint>
#include <cstddef>

// ---- constants from the reference config (exact fp32 images of the Python doubles) ----
#define C_DECAY 0.99f   // (1.0 - alpha), alpha = 1.0/100.0
#define C_ALPHA 0.01f   // alpha
#define C_THR   0.58f   // IGNITE_THR
#define C_WTA   0.85f   // WTA_INH

#define P1_NPB  32      // neurons per block (phase 1)
#define P1_TILE 128     // timesteps staged per tile
#define P1_PAD  36      // padded row stride in floats (32 data + 4 pad) -> <=2-way bank conflict

// ---------------- Phase 1: exact EMA chains, boundary states every L steps ----------------
// grid: N/32 blocks; block: 128 threads (wave0 = compute over 32 neurons, wave1 = loader)
__global__ __launch_bounds__(128)
void gw_phase1(const float* __restrict__ spikes, const float* __restrict__ nmda0,
               float* __restrict__ bnd, float* __restrict__ nmda_final_out,
               int T, int N, int Ls) {
  __shared__ float sb[2][P1_TILE * P1_PAD];   // 2 x 18 KiB
  const int w    = threadIdx.x >> 6;
  const int lane = threadIdx.x & 63;
  const int n0   = blockIdx.x * P1_NPB;
  const int ntiles = T / P1_TILE;
  const int N4 = N >> 2;
  const float4* sp4 = (const float4*)spikes;
  const int Lm1 = (1 << Ls) - 1;

  // loader mapping: each round covers 8 rows; lane -> row = lane>>3, float4-col = lane&7
  const int lrow = lane >> 3;
  const int lc4  = lane & 7;

  if (w == 1) {   // prologue: stage tile 0
#pragma unroll
    for (int rnd = 0; rnd < 16; ++rnd) {
      const int row = rnd * 8 + lrow;
      float4 v = sp4[(size_t)row * N4 + (n0 >> 2) + lc4];
      *(float4*)&sb[0][row * P1_PAD + lc4 * 4] = v;
    }
  }
  __syncthreads();

  float nmda = (w == 0 && lane < P1_NPB) ? nmda0[n0 + lane] : 0.0f;
  const int cl = lane & (P1_NPB - 1);   // upper lanes duplicate lower lanes (no stores)

  for (int tile = 0; tile < ntiles; ++tile) {
    const int cur = tile & 1;
    if (w == 0) {
      const float* buf = sb[cur];
      const int t0 = tile * P1_TILE;
      float s_cur[16], s_nxt[16];
#pragma unroll
      for (int i = 0; i < 16; ++i) s_cur[i] = buf[i * P1_PAD + cl];
#pragma unroll
      for (int j = 0; j < 8; ++j) {
        if (j < 7) {
#pragma unroll
          for (int i = 0; i < 16; ++i) s_nxt[i] = buf[((j + 1) * 16 + i) * P1_PAD + cl];
        }
        const int tb = t0 + j * 16;
        if ((tb & Lm1) == 0 && lane < P1_NPB)
          bnd[(size_t)(tb >> Ls) * N + n0 + lane] = nmda;
        // exact replica of the reference op order (no FMA contraction)
#pragma unroll
        for (int i = 0; i < 16; ++i)
          nmda = __fadd_rn(__fmul_rn(C_DECAY, nmda), __fmul_rn(C_ALPHA, s_cur[i]));
#pragma unroll
        for (int i = 0; i < 16; ++i) s_cur[i] = s_nxt[i];
      }
    } else if (tile + 1 < ntiles) {
      const int t0 = (tile + 1) * P1_TILE;
#pragma unroll
      for (int rnd = 0; rnd < 16; ++rnd) {
        const int row = rnd * 8 + lrow;
        float4 v = sp4[(size_t)(t0 + row) * N4 + (n0 >> 2) + lc4];
        *(float4*)&sb[cur ^ 1][row * P1_PAD + lc4 * 4] = v;
      }
    }
    __syncthreads();
  }
  if (w == 0 && lane < P1_NPB) nmda_final_out[n0 + lane] = nmda;
}

// lexicographic merge of two (score desc, index asc) top-2 tuples
__device__ __forceinline__ void merge2(float& a1, int& i1, float& a2, int& i2,
                                       float b1, int j1, float b2, int j2) {
  const bool afirst = (a1 > b1) || (a1 == b1 && i1 < j1);
  const float w1 = afirst ? a1 : b1; const int wi1 = afirst ? i1 : j1;
  const float l1 = afirst ? b1 : a1; const int li1 = afirst ? j1 : i1;
  const float cc = afirst ? a2 : b2; const int ci  = afirst ? i2 : j2;
  const bool sfirst = (cc > l1) || (cc == l1 && ci < li1);
  a1 = w1; i1 = wi1;
  a2 = sfirst ? cc : l1; i2 = sfirst ? ci : li1;
}

// ---------------- Phase 2: recompute rows from exact boundary, stable top-2, write outputs ----------------
// grid: C = T/L blocks; block: N/4 = 1024 threads (16 waves). 2 barriers per 16-row group.
__global__ __launch_bounds__(1024)
void gw_phase2(const float* __restrict__ spikes, const float* __restrict__ bnd,
               float* __restrict__ mask, float* __restrict__ cov,
               int T, int N, int L, float covval) {
  const int tid  = threadIdx.x;            // [0, N/4)
  const int lane = tid & 63;
  const int wv   = tid >> 6;               // wave id [0,16)
  const int N4   = N >> 2;
  const float4* sp4 = (const float4*)spikes;
  float4* mk4 = (float4*)mask;

  __shared__ float ws1[16][16]; __shared__ int wi1s[16][16];
  __shared__ float ws2[16][16]; __shared__ int wi2s[16][16];
  __shared__ float wmx[16][16];
  __shared__ int gj1[16], gj2[16];

  float4 nm = ((const float4*)bnd)[(size_t)blockIdx.x * N4 + tid];   // exact state before chunk
  const int base = tid * 4;
  const int t00  = blockIdx.x * L;

  for (int g = 0; g < L; g += 16) {
    const int tg = t00 + g;

    // ---------- pass A: 16 rows of EMA + per-wave stable top-2 ----------
#pragma unroll
    for (int r = 0; r < 16; ++r) {
      const float4 s = sp4[(size_t)(tg + r) * N4 + tid];

      nm.x = __fadd_rn(__fmul_rn(C_DECAY, nm.x), __fmul_rn(C_ALPHA, s.x));
      nm.y = __fadd_rn(__fmul_rn(C_DECAY, nm.y), __fmul_rn(C_ALPHA, s.y));
      nm.z = __fadd_rn(__fmul_rn(C_DECAY, nm.z), __fmul_rn(C_ALPHA, s.z));
      nm.w = __fadd_rn(__fmul_rn(C_DECAY, nm.w), __fmul_rn(C_ALPHA, s.w));

      const float c0 = __fmul_rn(nm.x, C_WTA);
      const float c1 = __fmul_rn(nm.y, C_WTA);
      const float c2 = __fmul_rn(nm.z, C_WTA);
      const float c3 = __fmul_rn(nm.w, C_WTA);

      float mx = fmaxf(fmaxf(nm.x, nm.y), fmaxf(nm.z, nm.w));

      // local stable top-2 (lowest index wins ties, like lax.top_k)
      float a1 = c0; int i1 = base;
      float a2 = -__builtin_inff(); int i2 = 0x7fffffff;
      if (c1 > a1) { a2 = a1; i2 = i1; a1 = c1; i1 = base + 1; }
      else if (c1 > a2) { a2 = c1; i2 = base + 1; }
      if (c2 > a1) { a2 = a1; i2 = i1; a1 = c2; i1 = base + 2; }
      else if (c2 > a2) { a2 = c2; i2 = base + 2; }
      if (c3 > a1) { a2 = a1; i2 = i1; a1 = c3; i1 = base + 3; }
      else if (c3 > a2) { a2 = c3; i2 = base + 3; }

      // wave butterfly (64 lanes)
#pragma unroll
      for (int m = 1; m < 64; m <<= 1) {
        const float b1 = __shfl_xor(a1, m, 64); const int j1 = __shfl_xor(i1, m, 64);
        const float b2 = __shfl_xor(a2, m, 64); const int j2 = __shfl_xor(i2, m, 64);
        mx = fmaxf(mx, __shfl_xor(mx, m, 64));
        merge2(a1, i1, a2, i2, b1, j1, b2, j2);
      }
      if (lane == 0) { ws1[r][wv] = a1; wi1s[r][wv] = i1; ws2[r][wv] = a2; wi2s[r][wv] = i2; wmx[r][wv] = mx; }
    }
    __syncthreads();

    // ---------- pass B: cross-wave reduce, 4 waves x 4 rows (16-lane groups) ----------
    if (wv < 4) {
      const int row = wv * 4 + (lane >> 4);
      const int q = lane & 15;
      float a1 = ws1[row][q]; int i1 = wi1s[row][q];
      float a2 = ws2[row][q]; int i2 = wi2s[row][q];
      float gm = wmx[row][q];
#pragma unroll
      for (int m = 1; m < 16; m <<= 1) {
        const float b1 = __shfl_xor(a1, m, 64); const int j1 = __shfl_xor(i1, m, 64);
        const float b2 = __shfl_xor(a2, m, 64); const int j2 = __shfl_xor(i2, m, 64);
        gm = fmaxf(gm, __shfl_xor(gm, m, 64));
        merge2(a1, i1, a2, i2, b1, j1, b2, j2);
      }
      if ((lane & 15) == 0) {
        const int ig = (gm >= C_THR) ? 1 : 0;
        gj1[row] = ig ? i1 : -1;        // -1 sentinel: nothing matches -> zero row
        gj2[row] = ig ? i2 : -1;
        cov[tg + row] = ig ? covval : 0.0f;
      }
    }
    __syncthreads();

    // ---------- pass C: stream out 16 mask rows ----------
#pragma unroll
    for (int r = 0; r < 16; ++r) {
      const int j1 = gj1[r], j2 = gj2[r];
      float4 v;
      v.x = (j1 == base     || j2 == base)     ? 1.0f : 0.0f;
      v.y = (j1 == base + 1 || j2 == base + 1) ? 1.0f : 0.0f;
      v.z = (j1 == base + 2 || j2 == base + 2) ? 1.0f : 0.0f;
      v.w = (j1 == base + 3 || j2 == base + 3) ? 1.0f : 0.0f;
      mk4[(size_t)(tg + r) * N4 + tid] = v;
    }
    if (g + 16 < L) __syncthreads();   // protect LDS reuse across groups
  }
}

extern "C" void kernel_launch(void* const* d_in, const int* in_sizes, int n_in,
                              void* d_out, int out_size, void* d_ws, size_t ws_size,
                              hipStream_t stream) {
  const float* spikes = (const float*)d_in[0];
  const float* nmda0  = (const float*)d_in[1];
  const int N = in_sizes[1];
  const int T = in_sizes[0] / N;

  float* out  = (float*)d_out;
  float* mask = out;                               // [T, N]
  float* cov  = out + (size_t)T * N;               // [T]
  float* nmf  = cov + T;                           // [N]

  // boundary-state chunk length L = 1<<Ls; shrink boundary count if ws is small
  int Ls = 4;
  while (((size_t)(T >> Ls)) * (size_t)N * sizeof(float) > ws_size && Ls < 13) ++Ls;
  const int L = 1 << Ls;
  const int C = T / L;
  float* bnd = (float*)d_ws;                       // [C, N]

  gw_phase1<<<N / P1_NPB, 128, 0, stream>>>(spikes, nmda0, bnd, nmf, T, N, Ls);
  gw_phase2<<<C, N / 4, 0, stream>>>(spikes, bnd, mask, cov, T, N, L, 2.0f / (float)N);
}